// Round 18
// baseline (114.606 us; speedup 1.0000x reference)
//
#include <hip/hip_runtime.h>
#include <stdint.h>

// ===========================================================================
// AnchorDataGenerator (Faster R-CNN anchor target layer), MI355X / gfx950
// Round 21: SYNC-FREE SPLIT (also the bisection experiment for the ~30us
// unexplained in the merged kernel). R20 validated early-default-emit ->
// the post-select stage only needs ~4K candidates, so:
//   memset(14.3KB ctrl) ->
//   k_compute (576 blocks, NO sync): champion compute + defaults for
//     non-candidates + push candidates (FG; BG m<BG_TC) into 64 hash-fanned
//     lists (~7 global atomics/block) + coarse hist + fanned totals. Exit.
//   k_resolve (64 blocks, NO sync): every block loads hist/totals (parallel
//     AG loads) and computes the IDENTICAL select (serial 256-bin scan);
//     block g resolves list g: below-bin -> kept, above -> default,
//     boundary-bin -> all blocks gather the same boundary set into LDS,
//     each ranks only its OWN members (exact, keys unique). Disjoint
//     writers; zero cross-block communication.
// Graph kernel boundary measured ~2us (R16->R17 delta) -> split is cheap.
// No barriers, no spins, no tree counters, no wake, no completer, no ZFLAG.
// Cross-dispatch visibility: standard stream ordering (proven R3-R8).
// ===========================================================================

#define NUM_A 9
#define HW 65536
#define N_ANCH 589824
#define NG 64
#define CAPK 128u
#define NBINS 256
#define BG_TC 65536u                     // BG coarse filter threshold on m
#define CLCAP 128u                       // per-list cap (BG exp ~55, 10σ)
#define BND_CAP 1024u                    // boundary staging (exp ~20-200)

#define LAB_BG 0u
#define LAB_FG 1u
#define LAB_IGN 2u

#define NBLK 576
#define NLIST 64

// workspace layout (u32 words)
#define OFF_HF    0                      // 256 fg hist (full range, >>15)
#define OFF_HB    256                    // 256 bg hist ([0,2^16), >>8)
#define OFF_TOTF  512                    // 32 x stride16 fg totals
#define OFF_TOTB  1024                   // 32 x stride16 bg totals
#define OFF_CCNTF 1536                   // 64 x stride16 fg list counters
#define OFF_CCNTB 2560                   // 64 x stride16 bg list counters
#define CTRL_WORDS 3584                  // 14.3 KB memset
#define OFF_LISTF CTRL_WORDS             // 3584 (byte 14336, 8B aligned)
#define OFF_LISTB (OFF_LISTF + 2*NLIST*CLCAP)  // 19968; end 36352 (~145 KB)

__constant__ float BA[NUM_A][4] = {
  { -84.f,  -40.f,  99.f,  55.f}, {-176.f,  -88.f, 191.f, 103.f},
  {-360.f, -184.f, 375.f, 199.f}, { -56.f,  -56.f,  71.f,  71.f},
  {-120.f, -120.f, 135.f, 135.f}, {-248.f, -248.f, 263.f, 263.f},
  { -36.f,  -80.f,  51.f,  95.f}, { -80.f, -168.f,  95.f, 183.f},
  {-168.f, -344.f, 183.f, 359.f}};

__host__ __device__ static inline void tf2x32(uint32_t k0, uint32_t k1,
                                              uint32_t x0, uint32_t x1,
                                              uint32_t* o0, uint32_t* o1) {
  const uint32_t ks2 = k0 ^ k1 ^ 0x1BD11BDAu;
#define TF_R(r) { x0 += x1; x1 = (x1 << (r)) | (x1 >> (32 - (r))); x1 ^= x0; }
  x0 += k0; x1 += k1;
  TF_R(13) TF_R(15) TF_R(26) TF_R(6)
  x0 += k1;  x1 += ks2 + 1u;
  TF_R(17) TF_R(29) TF_R(16) TF_R(24)
  x0 += ks2; x1 += k0 + 2u;
  TF_R(13) TF_R(15) TF_R(26) TF_R(6)
  x0 += k0;  x1 += k1 + 3u;
  TF_R(17) TF_R(29) TF_R(16) TF_R(24)
  x0 += k1;  x1 += ks2 + 4u;
  TF_R(13) TF_R(15) TF_R(26) TF_R(6)
  x0 += ks2; x1 += k0 + 5u;
#undef TF_R
  *o0 = x0; *o1 = x1;
}

__device__ static inline uint32_t mant_of(uint32_t k0, uint32_t k1, uint32_t n) {
  uint32_t o0, o1;
  tf2x32(k0, k1, 0u, n, &o0, &o1);
  return (o0 ^ o1) >> 9;                 // 23-bit mantissa
}

// Max of fl(iw) over valid integer shifts [lo,hi] for one axis (concave,
// unimodal; max at clamped floor/ceil of continuous argmax endpoints).
__device__ static inline float axis_best(float blo, float bhi, float glo,
                                         float ghi, int lo, int hi) {
  #pragma clang fp contract(off)
  float t1 = (ghi - bhi) * 0.0625f;
  float t2 = (glo - blo) * 0.0625f;
  float tmin = fminf(t1, t2), tmax = fmaxf(t1, t2);
  int c1 = (int)floorf(tmin), c2 = (int)ceilf(tmax);
  int cand0 = lo, cand1 = hi;
  int cand2 = min(max(c1,     lo), hi);
  int cand3 = min(max(c1 + 1, lo), hi);
  int cand4 = min(max(c2 - 1, lo), hi);
  int cand5 = min(max(c2,     lo), hi);
  float best = -3.0e38f;
  int cands[6] = {cand0, cand1, cand2, cand3, cand4, cand5};
  #pragma unroll
  for (int i = 0; i < 6; i++) {
    float s = (float)(cands[i] << 4);
    float v = fminf(bhi + s, ghi) - fmaxf(blo + s, glo) + 1.0f;
    best = fmaxf(best, v);
  }
  return best;
}

#define AG_LOAD(p)      __hip_atomic_load((p), __ATOMIC_RELAXED, __HIP_MEMORY_SCOPE_AGENT)
#define AG_STORE(p, v)  __hip_atomic_store((p), (v), __ATOMIC_RELAXED, __HIP_MEMORY_SCOPE_AGENT)

// ---- k_compute: pure data-parallel; no inter-block sync ----
__global__ __launch_bounds__(256) void k_compute(const float* __restrict__ gt,
                                                 const int* __restrict__ imw_p,
                                                 const int* __restrict__ imh_p,
                                                 float* __restrict__ out_lab,
                                                 float* __restrict__ out_adj,
                                                 float* __restrict__ out_wts,
                                                 uint32_t* __restrict__ ws,
                                                 uint32_t kf0, uint32_t kf1,
                                                 uint32_t kb0, uint32_t kb1) {
  #pragma clang fp contract(off)
  __shared__ uint32_t sh[2 * NBINS];         // LDS hist
  __shared__ float sg0[NG], sg1[NG], sg2[NG], sg3[NG], sga[NG], sgm[NG];
  __shared__ uint32_t sgmU[NG];
  __shared__ unsigned long long sMask[4];
  __shared__ int sAnyZero;
  __shared__ uint32_t sCF, sCB;
  int tid = threadIdx.x;
  int b = blockIdx.x;
  int a = b >> 6, hb = (b & 63) << 2;        // anchor type, rows hb..hb+3

  ((uint2*)sh)[tid] = make_uint2(0, 0);      // zero 512-word LDS hist
  if (tid == 0) { sAnyZero = 0; sCF = 0u; sCB = 0u; }
  if (tid < NG) {
    const float4 g4 = ((const float4*)gt)[tid];
    sg0[tid] = g4.x; sg1[tid] = g4.y; sg2[tid] = g4.z; sg3[tid] = g4.w;
    float gw = g4.z - g4.x + 1.0f, gh = g4.w - g4.y + 1.0f;
    sga[tid] = (gw > 0.0f && gh > 0.0f) ? gw * gh : 0.0f;
    sgmU[tid] = 0u;
  }
  __syncthreads();   // S1

  // local analytic gmax (LDS atomicMax on float bits; IoU >= 0)
  {
    int imwi = imw_p[0], imhi = imh_p[0];
    for (int p = tid; p < NG * NUM_A; p += 256) {
      int g = p / NUM_A, q = p - g * NUM_A;
      float b0 = BA[q][0], b1 = BA[q][1], b2 = BA[q][2], b3 = BA[q][3];
      int ib0 = (int)b0, ib1 = (int)b1, ib2 = (int)b2, ib3 = (int)b3;
      int wlo = max(0, (-ib0 + 15) >> 4);
      int whi = min(255, (imwi - ib2 - 1) >> 4);
      int hlo = max(0, (-ib1 + 15) >> 4);
      int hhi = min(255, (imhi - ib3 - 1) >> 4);
      if (wlo > whi || hlo > hhi) continue;
      float iwb = axis_best(b0, b2, sg0[g], sg2[g], wlo, whi);
      float ihb = axis_best(b1, b3, sg1[g], sg3[g], hlo, hhi);
      float aw = b2 - b0 + 1.0f, ah = b3 - b1 + 1.0f;
      float aarea = aw * ah;
      float inter = (iwb > 0.0f && ihb > 0.0f) ? iwb * ihb : 0.0f;
      float den = aarea + sga[g] - inter;
      float o = inter / den;
      atomicMax(&sgmU[g], __float_as_uint(o));
    }
  }

  // per-wave y-mask
  {
    int wv = tid >> 6, g = tid & 63;
    float sy = (float)((hb + wv) << 4);
    float ihp = fminf(BA[a][3] + sy, sg3[g]) - fmaxf(BA[a][1] + sy, sg1[g]) + 1.0f;
    unsigned long long mk = __ballot(ihp > 0.0f);
    if (g == 0) sMask[wv] = mk;
  }
  __syncthreads();   // S2
  if (tid < NG) {
    uint32_t mm = sgmU[tid];
    sgm[tid] = __uint_as_float(mm);
    if (mm == 0u) atomicOr(&sAnyZero, 1);
  }
  __syncthreads();   // S3

  float BA0 = BA[a][0], BA1 = BA[a][1], BA2 = BA[a][2], BA3 = BA[a][3];
  float imw = (float)imw_p[0], imh = (float)imh_p[0];
  int w = tid;
  float sx = (float)(w << 4);
  float A0 = BA0 + sx, A2 = BA2 + sx;
  float aw = A2 - A0 + 1.0f;
  float A1v[4], A3v[4];
  #pragma unroll
  for (int r = 0; r < 4; r++) {
    float sy = (float)((hb + r) << 4);
    A1v[r] = BA1 + sy; A3v[r] = BA3 + sy;
  }
  float ah = A3v[0] - A1v[0] + 1.0f;
  float aarea = aw * ah;                   // exact ints -> bit-exact
  bool xv = (A0 >= 0.0f) && (A2 < imw);

  unsigned long long mk0 = sMask[0], mk1 = sMask[1],
                     mk2 = sMask[2], mk3 = sMask[3];
  unsigned long long uni = mk0 | mk1 | mk2 | mk3;
  float amaxv[4] = {0.f, 0.f, 0.f, 0.f};
  int bgv[4] = {0, 0, 0, 0};
  uint32_t afv = 0u;
  while (uni) {
    int g = __ffsll(uni) - 1;
    uni &= uni - 1;
    float iw = fminf(A2, sg2[g]) - fmaxf(A0, sg0[g]) + 1.0f;
    if (!__any(iw > 0.0f)) continue;
    if (iw > 0.0f) {
      float base = aarea + sga[g];
      float gy1 = sg1[g], gy2 = sg3[g], gm = sgm[g];
#define DO_ROW(r, mk)                                                     \
      if ((mk >> g) & 1ull) {                                             \
        float ih = fminf(A3v[r], gy2) - fmaxf(A1v[r], gy1) + 1.0f;        \
        float inter = iw * ih;                                            \
        float o = inter / (base - inter);                                 \
        if (o > amaxv[r]) { amaxv[r] = o; bgv[r] = g; }                   \
        if (o == gm) afv |= (1u << r);                                    \
      }
      DO_ROW(0, mk0) DO_ROW(1, mk1) DO_ROW(2, mk2) DO_ROW(3, mk3)
#undef DO_ROW
    }
  }

  bool anyZ = (sAnyZero != 0);
  uint32_t cfLoc = 0, cbLoc = 0;
  #pragma unroll
  for (int r = 0; r < 4; r++) {
    int hw = (hb + r) * 256 + w;
    bool valid = xv && (A1v[r] >= 0.0f) && (A3v[r] < imh);
    float amax = amaxv[r];
    bool anyfg = (((afv >> r) & 1u) || anyZ) && valid;
    uint32_t lab;
    if (!valid)                       lab = LAB_IGN;
    else if (anyfg || amax >= 0.7f)   lab = LAB_FG;
    else if (amax < 0.3f)             lab = LAB_BG;
    else                              lab = LAB_IGN;

    float adj0 = 0.f, adj1 = 0.f, adj2 = 0.f, adj3 = 0.f;
    if (valid) {
      int bg = bgv[r];
      float G0 = sg0[bg], G1 = sg1[bg], G2 = sg2[bg], G3 = sg3[bg];
      float ax = (A2 + A0) * 0.5f, ay = (A3v[r] + A1v[r]) * 0.5f;
      float gwm = G2 - G0 + 1.0f, ghm = G3 - G1 + 1.0f;
      float gx = (G2 + G0) * 0.5f, gy = (G3 + G1) * 0.5f;
      adj0 = (gx - ax) / aw;
      adj1 = (gy - ay) / ah;
      adj2 = logf(gwm / aw);
      adj3 = logf(ghm / ah);
    }
    int c4 = a * 4;
    out_adj[(c4 + 0) * HW + hw] = adj0;
    out_adj[(c4 + 1) * HW + hw] = adj1;
    out_adj[(c4 + 2) * HW + hw] = adj2;
    out_adj[(c4 + 3) * HW + hw] = adj3;

    uint32_t m = 0u;
    uint32_t n = (uint32_t)(hw * 9 + a);   // original anchor index (tie-break)
    if (lab != LAB_IGN) {
      uint32_t kk0 = (lab == LAB_FG) ? kf0 : kb0;
      uint32_t kk1 = (lab == LAB_FG) ? kf1 : kb1;
      m = mant_of(kk0, kk1, n);
      if (lab == LAB_FG) {
        cfLoc++;
        atomicAdd(&sh[m >> 15], 1u);                   // FG: full range >>15
      } else {
        cbLoc++;
        if (m < BG_TC) atomicAdd(&sh[NBINS + (m >> 8)], 1u);  // BG: coarse
      }
    }

    bool cand = (lab == LAB_FG) || (lab == LAB_BG && m < BG_TC);
    if (cand) {
      // push to hash-fanned list (read by k_resolve next dispatch)
      int cls = (lab == LAB_FG) ? 0 : 1;
      uint32_t grp = (n * 2654435761u) >> 26;          // uniform 0..63
      uint32_t idx = atomicAdd(
          &ws[(cls ? OFF_CCNTB : OFF_CCNTF) + grp * 16], 1u);
      if (idx < CLCAP) {
        uint64_t* lst = (uint64_t*)(ws + (cls ? OFF_LISTB : OFF_LISTF)) +
                        grp * CLCAP;
        lst[idx] = ((uint64_t)m << 20) | (uint64_t)n;  // plain store
      }
    } else {
      // default emit (select-independent): IGN, and BG outside top-128
      out_lab[a * HW + hw] = 2.0f;
      out_wts[(c4 + 0) * HW + hw] = 0.0f;
      out_wts[(c4 + 1) * HW + hw] = 0.0f;
      out_wts[(c4 + 2) * HW + hw] = 0.0f;
      out_wts[(c4 + 3) * HW + hw] = 0.0f;
    }
  }
  if (cfLoc) atomicAdd(&sCF, cfLoc);
  if (cbLoc) atomicAdd(&sCB, cbLoc);
  __syncthreads();

  // global hist add (~9 atomics/block) + fanned totals
  for (int i = tid; i < 2 * NBINS; i += 256) {
    uint32_t v = sh[i];
    if (v) atomicAdd(&ws[OFF_HF + i], v);
  }
  if (tid == 0) {
    if (sCF) atomicAdd(&ws[OFF_TOTF + (b & 31) * 16], sCF);
    if (sCB) atomicAdd(&ws[OFF_TOTB + (b & 31) * 16], sCB);
  }
  // no barrier, no drain: kernel end performs the release.
}

// ---- k_resolve: 64 blocks, no inter-block sync; replicated select ----
__global__ __launch_bounds__(256) void k_resolve(float* __restrict__ out_lab,
                                                 float* __restrict__ out_wts,
                                                 uint32_t* __restrict__ ws) {
  __shared__ uint32_t sHist[2 * NBINS];      // 2 KB
  __shared__ uint32_t sT[64];
  __shared__ uint32_t sCnt[NLIST];
  __shared__ uint32_t sSel[8];               // {mode,bb,need,K} x2
  __shared__ float sInvS;
  __shared__ uint64_t sBnd[BND_CAP];         // 8 KB
  __shared__ uint32_t sBndCnt;
  int tid = threadIdx.x;
  int b = blockIdx.x;

  sHist[tid] = AG_LOAD(&ws[OFF_HF + tid]);
  sHist[NBINS + tid] = AG_LOAD(&ws[OFF_HF + NBINS + tid]);
  if (tid < 32)      sT[tid] = AG_LOAD(&ws[OFF_TOTF + tid * 16]);
  else if (tid < 64) sT[tid] = AG_LOAD(&ws[OFF_TOTB + (tid - 32) * 16]);
  __syncthreads();
  if (tid == 0) {
    uint32_t totF = 0, totB = 0;
    for (int i = 0; i < 32; i++) { totF += sT[i]; totB += sT[32 + i]; }
    uint32_t Kf = totF < CAPK ? totF : CAPK;
    uint32_t Kb = totB < CAPK ? totB : CAPK;
    sInvS = 1.0f / (float)(Kf + Kb);
    for (int cls = 0; cls < 2; cls++) {
      uint32_t tot = cls ? totB : totF;
      uint32_t K = tot < CAPK ? tot : CAPK;
      uint32_t mode = (K == 0u) ? 0u : ((tot <= CAPK) ? 1u : 2u);
      uint32_t bb = 0xFFFFFFFFu, need = 0u;
      if (mode == 2u) {
        uint32_t cum = 0;
        for (int i = 0; i < NBINS; i++) {
          uint32_t c = sHist[cls * NBINS + i];
          if (cum + c >= K) { bb = (uint32_t)i; need = K - cum; break; }
          cum += c;
        }
      }
      sSel[cls * 4 + 0] = mode; sSel[cls * 4 + 1] = bb;
      sSel[cls * 4 + 2] = need; sSel[cls * 4 + 3] = K;
    }
  }
  __syncthreads();
  float inv = sInvS;

  for (int cls = 0; cls < 2; cls++) {
    if (tid < NLIST) {
      uint32_t c = AG_LOAD(&ws[(cls ? OFF_CCNTB : OFF_CCNTF) + tid * 16]);
      sCnt[tid] = c < CLCAP ? c : CLCAP;
    }
    if (tid == 0) sBndCnt = 0u;
    __syncthreads();
    uint32_t mode = sSel[cls * 4 + 0], bb = sSel[cls * 4 + 1];
    uint32_t need = sSel[cls * 4 + 2];
    const uint64_t* lst0 =
        (const uint64_t*)(ws + (cls ? OFF_LISTB : OFF_LISTF));
    for (uint32_t idx = tid; idx < NLIST * CLCAP; idx += 256) {
      uint32_t g = idx >> 7, i = idx & (CLCAP - 1u);   // CLCAP = 128
      if (i >= sCnt[g]) continue;
      uint64_t k = lst0[g * CLCAP + i];                // prev-dispatch data
      uint32_t m = (uint32_t)(k >> 20);
      uint32_t n = (uint32_t)(k & 0xFFFFFu);
      bool own = (g == (uint32_t)b);
      bool decided = true, kept = false;
      if (mode == 1u) kept = true;
      else if (mode == 2u) {
        uint32_t bn = cls ? (m >> 8) : (m >> 15);
        if (bn < bb) kept = true;
        else if (bn == bb) {
          uint32_t s = atomicAdd(&sBndCnt, 1u);
          if (s < BND_CAP) {
            sBnd[s] = k | (own ? 0x8000000000000000ull : 0ull);
            decided = false;
          }
        }
      }
      if (own && decided) {
        uint32_t aa = n % 9u, hww = n / 9u;
        uint32_t tt = aa * HW + hww;
        out_lab[tt] = kept ? (cls == 0 ? 1.0f : 0.0f) : 2.0f;
        float wvv = (kept && cls == 0) ? inv : 0.0f;
        #pragma unroll
        for (int j2 = 0; j2 < 4; j2++)
          out_wts[(aa * 4 + j2) * HW + hww] = wvv;
      }
    }
    __syncthreads();
    uint32_t C = sBndCnt < BND_CAP ? sBndCnt : BND_CAP;
    for (uint32_t i = tid; i < C; i += 256) {
      uint64_t kk = sBnd[i];
      if (!(kk >> 63)) continue;                       // not my entry
      uint64_t key = kk & 0x7FFFFFFFFFFFFFFFull;
      uint32_t rr = 0;
      for (uint32_t j = 0; j < C; j++)
        rr += ((sBnd[j] & 0x7FFFFFFFFFFFFFFFull) < key) ? 1u : 0u;
      bool kept = (rr < need);                         // keys unique -> exact
      uint32_t n = (uint32_t)(key & 0xFFFFFu);
      uint32_t aa = n % 9u, hww = n / 9u;
      uint32_t tt = aa * HW + hww;
      out_lab[tt] = kept ? (cls == 0 ? 1.0f : 0.0f) : 2.0f;
      float wvv = (kept && cls == 0) ? inv : 0.0f;
      #pragma unroll
      for (int j2 = 0; j2 < 4; j2++)
        out_wts[(aa * 4 + j2) * HW + hww] = wvv;
    }
    __syncthreads();
  }
}

extern "C" void kernel_launch(void* const* d_in, const int* in_sizes, int n_in,
                              void* d_out, int out_size, void* d_ws,
                              size_t ws_size, hipStream_t stream) {
  const float* gt  = (const float*)d_in[1];
  const int*   imw = (const int*)d_in[2];
  const int*   imh = (const int*)d_in[3];
  float* out      = (float*)d_out;
  float* out_lab  = out;                   // 589824
  float* out_adj  = out + N_ANCH;          // 4*589824
  float* out_wts  = out + 5 * N_ANCH;      // 4*589824
  uint32_t* ws = (uint32_t*)d_ws;          // ~145 KB used

  uint32_t kf0, kf1, kb0, kb1;
  tf2x32(0u, 42u, 0u, 0u, &kf0, &kf1);
  tf2x32(0u, 42u, 0u, 1u, &kb0, &kb1);

  hipMemsetAsync(ws, 0, CTRL_WORDS * sizeof(uint32_t), stream);
  hipLaunchKernelGGL(k_compute, dim3(NBLK), dim3(256), 0, stream, gt, imw,
                     imh, out_lab, out_adj, out_wts, ws, kf0, kf1, kb0, kb1);
  hipLaunchKernelGGL(k_resolve, dim3(NLIST), dim3(256), 0, stream, out_lab,
                     out_wts, ws);
}